// Round 6
// baseline (86.473 us; speedup 1.0000x reference)
//
#include <hip/hip_runtime.h>
#include <hip/hip_bf16.h>

typedef unsigned int uint32;
typedef unsigned short u16;

#define NPT 128        // grid nodes per dim
#define RNK 16         // TT rank
#define ROW_U16 256    // mid-core row = 512 B swizzled, bank-tiled for 8-lane groups
#define ROW_U32 128
#define EDGEROW 20     // fp32 elems per edge row (16 + 4 pad) = 80 B
#define CORE_U32 (NPT*ROW_U32)          // 16384 u32 per swizzled bf16 core
#define CORE_BYTES (CORE_U32*4)         // 65536 B
#define SMEM_AB (CORE_BYTES + NPT*EDGEROW*4)   // 65536 + 10240 = 75776 B -> 2 blocks/CU
// fallback (single-kernel R5) LDS
#define NWAVES 16
#define SMEM_FB (2*NPT*ROW_U16*2 + 2*NPT*EDGEROW*4 + 2*NWAVES*64*4)  // 159744 B

#if defined(__has_builtin)
#if __has_builtin(__builtin_amdgcn_fdot2_f32_bf16)
#define HAVE_BFDOT2 1
#endif
#endif

__device__ __forceinline__ float bl(uint32 u){ return __uint_as_float(u << 16); }
__device__ __forceinline__ float bh(uint32 u){ return __uint_as_float(u & 0xffff0000u); }

#ifdef HAVE_BFDOT2
typedef __bf16 v2bf __attribute__((ext_vector_type(2)));
__device__ __forceinline__ v2bf bc(uint32 u){ return __builtin_bit_cast(v2bf, u); }
__device__ __forceinline__ float dot8(const uint32* vp, uint4 U) {
  float s = 0.f;
  s = __builtin_amdgcn_fdot2_f32_bf16(bc(vp[0]), bc(U.x), s, false);
  s = __builtin_amdgcn_fdot2_f32_bf16(bc(vp[1]), bc(U.y), s, false);
  s = __builtin_amdgcn_fdot2_f32_bf16(bc(vp[2]), bc(U.z), s, false);
  s = __builtin_amdgcn_fdot2_f32_bf16(bc(vp[3]), bc(U.w), s, false);
  return s;
}
#else
__device__ __forceinline__ float dot8(const uint32* vp, uint4 U) {
  float s = fmaf(bh(vp[0]), bh(U.x), bl(vp[0]) * bl(U.x));
  s = fmaf(bl(vp[1]), bl(U.y), s); s = fmaf(bh(vp[1]), bh(U.y), s);
  s = fmaf(bl(vp[2]), bl(U.z), s); s = fmaf(bh(vp[2]), bh(U.z), s);
  s = fmaf(bl(vp[3]), bl(U.w), s); s = fmaf(bh(vp[3]), bh(U.w), s);
  return s;
}
#endif

__device__ __forceinline__ uint32 packbf(float a, float b) {
  __hip_bfloat16 l = __float2bfloat16(a), h = __float2bfloat16(b);
  return (uint32)(*(u16*)&l) | ((uint32)(*(u16*)&h) << 16);
}

__device__ __forceinline__ float remap_clamp(float x) {
  float xr = (x + 1.0f) * 0.5f * (float)(NPT - 1);
  return fminf(fmaxf(xr, 0.0f), (float)(NPT - 1));
}

// 8-lane butterfly allgather: lane q holds u32 m = packed cols(2q,2q+1);
// afterwards vp[0..7] = all 16 cols in order. 7 shfl_xor, no lgkmcnt(0) drain.
__device__ __forceinline__ void allgather8(int q, uint32 m, uint32* vp) {
  uint32 o1 = (uint32)__shfl_xor((int)m, 1, 64);
  uint32 a0 = (q & 1) ? o1 : m;
  uint32 a1 = (q & 1) ? m : o1;
  uint32 b0 = (uint32)__shfl_xor((int)a0, 2, 64);
  uint32 b1 = (uint32)__shfl_xor((int)a1, 2, 64);
  uint32 c0 = (q & 2) ? b0 : a0;
  uint32 c1 = (q & 2) ? b1 : a1;
  uint32 c2 = (q & 2) ? a0 : b0;
  uint32 c3 = (q & 2) ? a1 : b1;
  uint32 d0 = (uint32)__shfl_xor((int)c0, 4, 64);
  uint32 d1 = (uint32)__shfl_xor((int)c1, 4, 64);
  uint32 d2 = (uint32)__shfl_xor((int)c2, 4, 64);
  uint32 d3 = (uint32)__shfl_xor((int)c3, 4, 64);
  if (q & 4) { vp[0]=d0; vp[1]=d1; vp[2]=d2; vp[3]=d3; vp[4]=c0; vp[5]=c1; vp[6]=c2; vp[7]=c3; }
  else       { vp[0]=c0; vp[1]=c1; vp[2]=c2; vp[3]=c3; vp[4]=d0; vp[5]=d1; vp[6]=d2; vp[7]=d3; }
}

// One mid-dim contraction, lane q of the point's 8-lane group.
// LDS u16 off = n*256 + slot*8 + (i&7), slot = (j>>1) + 8*(i>>3) + 16*(j&1):
// lane q's 4 fragments sit at bytes q*16 + {0,128,256,384} -> every wave-level
// ds_read_b128 hits each bank exactly 8x -> zero conflicts for any random rows.
__device__ __forceinline__ void mid_dim(const u16* __restrict__ c, float xc, int q,
                                        const uint32* vp, float& nv0, float& nv1)
{
  int n0 = (int)xc;
  float w = xc - (float)n0;
  int n1 = min(n0 + 1, NPT - 1);
  const uint32* r0 = (const uint32*)(c + n0 * ROW_U16) + q * 4;
  const uint32* r1 = (const uint32*)(c + n1 * ROW_U16) + q * 4;
  uint4 A0 = *(const uint4*)(r0);        // col 2q,   i 0-7,  row lo
  uint4 A1 = *(const uint4*)(r0 + 32);   // col 2q,   i 8-15, row lo
  uint4 A2 = *(const uint4*)(r0 + 64);   // col 2q+1, i 0-7,  row lo
  uint4 A3 = *(const uint4*)(r0 + 96);   // col 2q+1, i 8-15, row lo
  uint4 B0 = *(const uint4*)(r1);
  uint4 B1 = *(const uint4*)(r1 + 32);
  uint4 B2 = *(const uint4*)(r1 + 64);
  uint4 B3 = *(const uint4*)(r1 + 96);
  float a0 = dot8(vp, A0) + dot8(vp + 4, A1);
  float a1 = dot8(vp, B0) + dot8(vp + 4, B1);
  float b0 = dot8(vp, A2) + dot8(vp + 4, A3);
  float b1 = dot8(vp, B2) + dot8(vp + 4, B3);
  nv0 = fmaf(w, a1 - a0, a0);
  nv1 = fmaf(w, b1 - b0, b0);
}

// prep: cores fp32 [i][n][j] -> ws bf16 swizzled [n][slot][ipair] (u32 = (i,i+1) pair)
__global__ void prep_cores(const float* __restrict__ g1, const float* __restrict__ g2,
                           uint32* __restrict__ ws) {
  int t = blockIdx.x * blockDim.x + threadIdx.x;    // 0..32767
  const float* g = (t < CORE_U32) ? g1 : g2;
  int o = t & (CORE_U32 - 1);
  int n = o >> 7;
  int k = o & 127;
  int s = k >> 2;          // slot
  int ip = k & 3;          // i-pair within slot
  int j = ((s & 7) << 1) | (s >> 4);
  int i = ((s >> 3) & 1) * 8 + ip * 2;
  float lo = g[i * 2048 + n * 16 + j];
  float hi = g[(i + 1) * 2048 + n * 16 + j];
  ws[t] = packbf(lo, hi);
}

// Kernel A: dims 0+1. LDS = c1 (64 KB swizzled bf16) + c0 edges. 2 blocks/CU.
__global__ __launch_bounds__(1024, 8) void ttA(
    const float* __restrict__ x, const float* __restrict__ g0,
    const uint32* __restrict__ wsc, uint32* __restrict__ vbuf, int npts)
{
  extern __shared__ char smem[];
  u16* c1 = (u16*)smem;
  float* c0 = (float*)(smem + CORE_BYTES);

  // linear 64 KB copy of pre-swizzled core1 (conflict-free b128 writes)
  {
    const uint4* src = (const uint4*)wsc;      // core1 = ws[0 .. 16383]
    uint4* dst = (uint4*)c1;
    for (int t = threadIdx.x; t < CORE_U32 / 4; t += blockDim.x) dst[t] = src[t];
  }
  for (int t = threadIdx.x; t < NPT * RNK; t += blockDim.x)
    c0[(t >> 4) * EDGEROW + (t & 15)] = g0[t];
  __syncthreads();

  const int q = threadIdx.x & 7;
  const int ptb = threadIdx.x >> 3;
  for (int it = 0; it < 4; ++it) {
    int p = (blockIdx.x << 9) + (it << 7) + ptb;
    int pc = min(p, npts - 1);
    float2 xy = *(const float2*)(x + pc * 4);
    // dim 0
    float xc = remap_clamp(xy.x);
    int n0 = (int)xc; float w = xc - (float)n0; int n1 = min(n0 + 1, NPT - 1);
    float2 lo = *(const float2*)(c0 + n0 * EDGEROW + 2 * q);
    float2 hi = *(const float2*)(c0 + n1 * EDGEROW + 2 * q);
    float nv0 = fmaf(w, hi.x - lo.x, lo.x);
    float nv1 = fmaf(w, hi.y - lo.y, lo.y);
    uint32 vp[8];
    allgather8(q, packbf(nv0, nv1), vp);
    mid_dim(c1, remap_clamp(xy.y), q, vp, nv0, nv1);
    if (p < npts) vbuf[p * 8 + q] = packbf(nv0, nv1);  // 64 consecutive u32/wave
  }
}

// Kernel B: dims 2+3. LDS = c2 + c3 edges. 2 blocks/CU.
__global__ __launch_bounds__(1024, 8) void ttB(
    const float* __restrict__ x, const float* __restrict__ g3,
    const uint32* __restrict__ wsc, const uint32* __restrict__ vbuf,
    float* __restrict__ out, int npts)
{
  extern __shared__ char smem[];
  u16* c2 = (u16*)smem;
  float* c3 = (float*)(smem + CORE_BYTES);

  {
    const uint4* src = (const uint4*)(wsc + CORE_U32);   // core2 = ws[16384 .. 32767]
    uint4* dst = (uint4*)c2;
    for (int t = threadIdx.x; t < CORE_U32 / 4; t += blockDim.x) dst[t] = src[t];
  }
  for (int t = threadIdx.x; t < NPT * RNK; t += blockDim.x)
    c3[(t & 127) * EDGEROW + (t >> 7)] = g3[t];          // g3 [i][n] -> [n][i]
  __syncthreads();

  const int q = threadIdx.x & 7;
  const int ptb = threadIdx.x >> 3;
  for (int it = 0; it < 4; ++it) {
    int p = (blockIdx.x << 9) + (it << 7) + ptb;
    int pc = min(p, npts - 1);
    float2 zw = *(const float2*)(x + pc * 4 + 2);
    uint32 m = vbuf[pc * 8 + q];                         // coalesced
    uint32 vp[8];
    allgather8(q, m, vp);
    float nv0, nv1;
    mid_dim(c2, remap_clamp(zw.x), q, vp, nv0, nv1);
    // dim 3 + 8-lane reduce
    float xc = remap_clamp(zw.y);
    int n0 = (int)xc; float w = xc - (float)n0; int n1 = min(n0 + 1, NPT - 1);
    float2 lo = *(const float2*)(c3 + n0 * EDGEROW + 2 * q);
    float2 hi = *(const float2*)(c3 + n1 * EDGEROW + 2 * q);
    float part = fmaf(nv1, fmaf(w, hi.y - lo.y, lo.y), nv0 * fmaf(w, hi.x - lo.x, lo.x));
    part += __shfl_xor(part, 1, 64);
    part += __shfl_xor(part, 2, 64);
    part += __shfl_xor(part, 4, 64);
    if (q == 0 && p < npts) out[p] = part;
  }
}

// ---------------- fallback: round-5 single kernel (used if ws too small) ----------------
__device__ __forceinline__ void mid_dim2(const u16* __restrict__ c, float xcA, float xcB,
                                         int q, const uint32* vpA, const uint32* vpB,
                                         float& nA0, float& nA1, float& nB0, float& nB1)
{
  int a0 = (int)xcA; float wA = xcA - (float)a0; int a1 = min(a0 + 1, NPT - 1);
  int b0 = (int)xcB; float wB = xcB - (float)b0; int b1 = min(b0 + 1, NPT - 1);
  const uint32* rA0 = (const uint32*)(c + a0 * ROW_U16) + q * 4;
  const uint32* rA1 = (const uint32*)(c + a1 * ROW_U16) + q * 4;
  const uint32* rB0 = (const uint32*)(c + b0 * ROW_U16) + q * 4;
  const uint32* rB1 = (const uint32*)(c + b1 * ROW_U16) + q * 4;
  uint4 A0 = *(const uint4*)(rA0);      uint4 A1 = *(const uint4*)(rA0 + 32);
  uint4 A2 = *(const uint4*)(rA0 + 64); uint4 A3 = *(const uint4*)(rA0 + 96);
  uint4 A4 = *(const uint4*)(rA1);      uint4 A5 = *(const uint4*)(rA1 + 32);
  uint4 A6 = *(const uint4*)(rA1 + 64); uint4 A7 = *(const uint4*)(rA1 + 96);
  uint4 B0 = *(const uint4*)(rB0);      uint4 B1 = *(const uint4*)(rB0 + 32);
  uint4 B2 = *(const uint4*)(rB0 + 64); uint4 B3 = *(const uint4*)(rB0 + 96);
  uint4 B4 = *(const uint4*)(rB1);      uint4 B5 = *(const uint4*)(rB1 + 32);
  uint4 B6 = *(const uint4*)(rB1 + 64); uint4 B7 = *(const uint4*)(rB1 + 96);
  float aA0 = dot8(vpA, A0) + dot8(vpA + 4, A1);
  float aA1 = dot8(vpA, A4) + dot8(vpA + 4, A5);
  float bA0 = dot8(vpA, A2) + dot8(vpA + 4, A3);
  float bA1 = dot8(vpA, A6) + dot8(vpA + 4, A7);
  float aB0 = dot8(vpB, B0) + dot8(vpB + 4, B1);
  float aB1 = dot8(vpB, B4) + dot8(vpB + 4, B5);
  float bB0 = dot8(vpB, B2) + dot8(vpB + 4, B3);
  float bB1 = dot8(vpB, B6) + dot8(vpB + 4, B7);
  nA0 = fmaf(wA, aA1 - aA0, aA0);
  nA1 = fmaf(wA, bA1 - bA0, bA0);
  nB0 = fmaf(wB, aB1 - aB0, aB0);
  nB1 = fmaf(wB, bB1 - bB0, bB0);
}

__device__ __forceinline__ void exchange2(uint32* xchA, uint32* xchB, int lane,
                                          float nA0, float nA1, float nB0, float nB1,
                                          uint32* vpA, uint32* vpB)
{
  xchA[lane] = packbf(nA0, nA1);
  xchB[lane] = packbf(nB0, nB1);
  __asm__ volatile("s_waitcnt lgkmcnt(0)" ::: "memory");
  const uint4* a = (const uint4*)(xchA + (lane & 56));
  const uint4* b = (const uint4*)(xchB + (lane & 56));
  uint4 a0 = a[0], a1 = a[1], b0 = b[0], b1 = b[1];
  vpA[0]=a0.x; vpA[1]=a0.y; vpA[2]=a0.z; vpA[3]=a0.w;
  vpA[4]=a1.x; vpA[5]=a1.y; vpA[6]=a1.z; vpA[7]=a1.w;
  vpB[0]=b0.x; vpB[1]=b0.y; vpB[2]=b0.z; vpB[3]=b0.w;
  vpB[4]=b1.x; vpB[5]=b1.y; vpB[6]=b1.z; vpB[7]=b1.w;
}

__global__ __launch_bounds__(1024, 4) void tt_fb(
    const float* __restrict__ x,  const float* __restrict__ g0,
    const float* __restrict__ g1, const float* __restrict__ g2,
    const float* __restrict__ g3, float* __restrict__ out, int npts)
{
  extern __shared__ char smem[];
  u16* c1 = (u16*)smem;
  u16* c2 = c1 + NPT * ROW_U16;
  float* c0 = (float*)(c2 + NPT * ROW_U16);
  float* c3 = c0 + NPT * EDGEROW;
  uint32* xch = (uint32*)(c3 + NPT * EDGEROW);

  for (int t = threadIdx.x; t < RNK * NPT * RNK; t += blockDim.x) {
    int i = t >> 11;
    int n = (t >> 4) & (NPT - 1);
    int j = t & (RNK - 1);
    int slot = (j >> 1) + ((i >> 3) << 3) + ((j & 1) << 4);
    int off = n * ROW_U16 + slot * 8 + (i & 7);
    __hip_bfloat16 h1 = __float2bfloat16(g1[t]);
    __hip_bfloat16 h2 = __float2bfloat16(g2[t]);
    c1[off] = *(u16*)&h1;
    c2[off] = *(u16*)&h2;
  }
  for (int t = threadIdx.x; t < NPT * RNK; t += blockDim.x) {
    int n = t >> 4;
    int i = t & (RNK - 1);
    c0[n * EDGEROW + i] = g0[t];
    c3[n * EDGEROW + i] = g3[i * NPT + n];
  }
  __syncthreads();

  const int lane = threadIdx.x & 63;
  const int q = threadIdx.x & 7;
  uint32* xchA = xch + (threadIdx.x >> 6) * 128;
  uint32* xchB = xchA + 64;
  const int ptb = threadIdx.x >> 3;

  for (int it = 0; it < 4; ++it) {
    int pA = (blockIdx.x << 10) + (it << 8) + ptb;
    int pB = pA + 128;
    bool okA = pA < npts, okB = pB < npts;
    float4 xvA = reinterpret_cast<const float4*>(x)[okA ? pA : 0];
    float4 xvB = reinterpret_cast<const float4*>(x)[okB ? pB : 0];
    uint32 vpA[8], vpB[8];
    float nA0, nA1, nB0, nB1;
    {
      float xcA = remap_clamp(xvA.x);
      int n0 = (int)xcA; float w = xcA - (float)n0; int n1 = min(n0 + 1, NPT - 1);
      float2 lo = *(const float2*)(c0 + n0 * EDGEROW + 2 * q);
      float2 hi = *(const float2*)(c0 + n1 * EDGEROW + 2 * q);
      nA0 = fmaf(w, hi.x - lo.x, lo.x);
      nA1 = fmaf(w, hi.y - lo.y, lo.y);
      float xcB = remap_clamp(xvB.x);
      int m0 = (int)xcB; float u = xcB - (float)m0; int m1 = min(m0 + 1, NPT - 1);
      float2 lo2 = *(const float2*)(c0 + m0 * EDGEROW + 2 * q);
      float2 hi2 = *(const float2*)(c0 + m1 * EDGEROW + 2 * q);
      nB0 = fmaf(u, hi2.x - lo2.x, lo2.x);
      nB1 = fmaf(u, hi2.y - lo2.y, lo2.y);
    }
    exchange2(xchA, xchB, lane, nA0, nA1, nB0, nB1, vpA, vpB);
    mid_dim2(c1, remap_clamp(xvA.y), remap_clamp(xvB.y), q, vpA, vpB, nA0, nA1, nB0, nB1);
    exchange2(xchA, xchB, lane, nA0, nA1, nB0, nB1, vpA, vpB);
    mid_dim2(c2, remap_clamp(xvA.z), remap_clamp(xvB.z), q, vpA, vpB, nA0, nA1, nB0, nB1);
    {
      float xcA = remap_clamp(xvA.w);
      int n0 = (int)xcA; float w = xcA - (float)n0; int n1 = min(n0 + 1, NPT - 1);
      float2 lo = *(const float2*)(c3 + n0 * EDGEROW + 2 * q);
      float2 hi = *(const float2*)(c3 + n1 * EDGEROW + 2 * q);
      float xcB = remap_clamp(xvB.w);
      int m0 = (int)xcB; float u = xcB - (float)m0; int m1 = min(m0 + 1, NPT - 1);
      float2 lo2 = *(const float2*)(c3 + m0 * EDGEROW + 2 * q);
      float2 hi2 = *(const float2*)(c3 + m1 * EDGEROW + 2 * q);
      float pa = fmaf(nA1, fmaf(w, hi.y - lo.y, lo.y), nA0 * fmaf(w, hi.x - lo.x, lo.x));
      float pb = fmaf(nB1, fmaf(u, hi2.y - lo2.y, lo2.y), nB0 * fmaf(u, hi2.x - lo2.x, lo2.x));
      pa += __shfl_xor(pa, 1, 64);  pb += __shfl_xor(pb, 1, 64);
      pa += __shfl_xor(pa, 2, 64);  pb += __shfl_xor(pb, 2, 64);
      pa += __shfl_xor(pa, 4, 64);  pb += __shfl_xor(pb, 4, 64);
      if (q == 0) {
        if (okA) out[pA] = pa;
        if (okB) out[pB] = pb;
      }
    }
  }
}

extern "C" void kernel_launch(void* const* d_in, const int* in_sizes, int n_in,
                              void* d_out, int out_size, void* d_ws, size_t ws_size,
                              hipStream_t stream) {
  const float* x  = (const float*)d_in[0];
  const float* g0 = (const float*)d_in[1];
  const float* g1 = (const float*)d_in[2];
  const float* g2 = (const float*)d_in[3];
  const float* g3 = (const float*)d_in[4];
  float* out = (float*)d_out;

  int B = in_sizes[0] / 4;
  size_t ws_need = (size_t)2 * CORE_BYTES + (size_t)B * 32;  // cores + v-buffer

  if (ws_size >= ws_need) {
    uint32* ws = (uint32*)d_ws;
    uint32* vbuf = ws + 2 * CORE_U32;
    hipFuncSetAttribute(reinterpret_cast<const void*>(ttA),
                        hipFuncAttributeMaxDynamicSharedMemorySize, SMEM_AB);
    hipFuncSetAttribute(reinterpret_cast<const void*>(ttB),
                        hipFuncAttributeMaxDynamicSharedMemorySize, SMEM_AB);
    prep_cores<<<128, 256, 0, stream>>>(g1, g2, ws);
    int grid = (B + 511) / 512;   // 512 blocks -> 2 per CU
    ttA<<<grid, 1024, SMEM_AB, stream>>>(x, g0, ws, vbuf, B);
    ttB<<<grid, 1024, SMEM_AB, stream>>>(x, g3, ws, vbuf, out, B);
  } else {
    hipFuncSetAttribute(reinterpret_cast<const void*>(tt_fb),
                        hipFuncAttributeMaxDynamicSharedMemorySize, SMEM_FB);
    int grid = (B + 1023) / 1024;
    tt_fb<<<grid, 1024, SMEM_FB, stream>>>(x, g0, g1, g2, g3, out, B);
  }
}